// Round 4
// baseline (1056.482 us; speedup 1.0000x reference)
//
#include <hip/hip_runtime.h>
#include <hip/hip_bf16.h>

#define BN 2
#define SEQ 2048
#define DM 1024
#define NH 16
#define DK 64

using f32x4  = __attribute__((ext_vector_type(4))) float;
using bf16x8 = __attribute__((ext_vector_type(8))) __bf16;
using short8 = __attribute__((ext_vector_type(8))) short;

static_assert(sizeof(bf16x8) == 16, "bf16x8 must be 16B");

#define MFMA16(a, b, c) __builtin_amdgcn_mfma_f32_16x16x32_bf16(a, b, c, 0, 0, 0)

__device__ __forceinline__ unsigned short f2b(float f) {
    __hip_bfloat16 h = __float2bfloat16(f);
    return __builtin_bit_cast(unsigned short, h);
}

__device__ __forceinline__ bf16x8 load_bf8(const unsigned short* p) {
    short8 s = *reinterpret_cast<const short8*>(p);
    return __builtin_bit_cast(bf16x8, s);
}

// ---------------------------------------------------------------- bias table
__global__ void bias_table_kernel(const float* __restrict__ rel,
                                  float* __restrict__ bias_val,
                                  unsigned int* __restrict__ khmax) {
    int idx = blockIdx.x * 256 + threadIdx.x;
    if (blockIdx.x == 0 && threadIdx.x < BN * NH) khmax[threadIdx.x] = 0u;
    if (idx >= NH * 4095) return;
    int h = idx / 4095;
    int dd = idx - h * 4095;
    int d = dd - 2047;
    int a = d < 0 ? -d : d;
    int bucket;
    if (a == 0) bucket = 0;
    else if (a < 8) bucket = 16 + a;
    else {
        int k = (a >= 14) + (a >= 23) + (a >= 39) + (a >= 64) +
                (a >= 108) + (a >= 182) + (a >= 305);
        bucket = 24 + k;
    }
    bias_val[h * 4095 + dd] = rel[bucket * NH + h];
}

// ---------------------------------------------------------------- weight prep
__global__ __launch_bounds__(256) void wtrans_kernel(
        const float* __restrict__ W0, const float* __restrict__ W1,
        const float* __restrict__ W2, const float* __restrict__ W3,
        unsigned short* __restrict__ T0, unsigned short* __restrict__ T1,
        unsigned short* __restrict__ T2, unsigned short* __restrict__ T3) {
    constexpr int P = 68;
    __shared__ unsigned short lt[64 * P];
    const int mz = blockIdx.z;
    const float* W = mz == 0 ? W0 : mz == 1 ? W1 : mz == 2 ? W2 : W3;
    unsigned short* T = mz == 0 ? T0 : mz == 1 ? T1 : mz == 2 ? T2 : T3;
    const int k0 = blockIdx.x * 64, n0 = blockIdx.y * 64;
    const int tid = threadIdx.x;
#pragma unroll
    for (int p = 0; p < 4; ++p) {
        int r = p * 16 + (tid >> 4);
        int c = (tid & 15) * 4;
        float4 vv = *(const float4*)&W[(size_t)(k0 + r) * DM + n0 + c];
#pragma unroll
        for (int j = 0; j < 4; ++j) {
            int n = c + j;
            float x = j == 0 ? vv.x : j == 1 ? vv.y : j == 2 ? vv.z : vv.w;
            lt[n * P + (r ^ ((n & 7) << 3))] = f2b(x);
        }
    }
    __syncthreads();
#pragma unroll
    for (int p = 0; p < 2; ++p) {
        int rn = p * 32 + (tid >> 3);
        int ck = (tid & 7) * 8;
        int ckx = ck ^ ((rn & 7) << 3);
        ushort4 a0 = *(ushort4*)&lt[rn * P + ckx];
        ushort4 a1 = *(ushort4*)&lt[rn * P + ckx + 4];
        *(ushort4*)&T[(size_t)(n0 + rn) * DM + k0 + ck] = a0;
        *(ushort4*)&T[(size_t)(n0 + rn) * DM + k0 + ck + 4] = a1;
    }
}

// ---------------------------------------------------------------- fused QKV GEMM
// z=0: Q natural bf16 *0.125 (+row norms); z=1: K head-major (+head max norms);
// z=2: V -> Vt[b][h][d][s]
__global__ __launch_bounds__(256) void qkv_gemm(
        const float* __restrict__ Aq, const float* __restrict__ Ak, const float* __restrict__ Av,
        const unsigned short* __restrict__ Wtq, const unsigned short* __restrict__ Wtk,
        const unsigned short* __restrict__ Wtv,
        const float* __restrict__ bq, const float* __restrict__ bk, const float* __restrict__ bv,
        unsigned short* __restrict__ Qp, unsigned short* __restrict__ Kh,
        unsigned short* __restrict__ Vt,
        float* __restrict__ qnorm, unsigned int* __restrict__ khmax) {
    constexpr int KP = 40;
    __shared__ unsigned short la[128 * KP];
    __shared__ unsigned short lb[128 * KP];
    const int mat = blockIdx.z;
    const float* A = mat == 0 ? Aq : mat == 1 ? Ak : Av;
    const unsigned short* Wt = mat == 0 ? Wtq : mat == 1 ? Wtk : Wtv;
    const float* bias = mat == 0 ? bq : mat == 1 ? bk : bv;
    const float outscale = mat == 0 ? 0.125f : 1.0f;
    const int tid = threadIdx.x;
    const int m0 = blockIdx.y * 128, n0 = blockIdx.x * 128;
    const int lane = tid & 63, wid = tid >> 6;
    const int wm0 = (wid >> 1) * 64, wn0 = (wid & 1) * 64;
    const int l15 = lane & 15, l4 = lane >> 4;
    f32x4 acc[4][4] = {};

    for (int kt = 0; kt < 32; ++kt) {
        const int k0 = kt * 32;
#pragma unroll
        for (int i = 0; i < 4; ++i) {
            int idx = tid + i * 256;
            int row = idx >> 3, c4 = (idx & 7) * 4;
            float4 v = *(const float4*)(A + (size_t)(m0 + row) * DM + k0 + c4);
            ushort4 u; u.x = f2b(v.x); u.y = f2b(v.y); u.z = f2b(v.z); u.w = f2b(v.w);
            *(ushort4*)&la[row * KP + c4] = u;
        }
#pragma unroll
        for (int i = 0; i < 2; ++i) {
            int idx = tid + i * 256;
            int row = idx >> 2, c8 = (idx & 3) * 8;
            *(int4*)&lb[row * KP + c8] =
                *(const int4*)&Wt[(size_t)(n0 + row) * DM + k0 + c8];
        }
        __syncthreads();
        bf16x8 af[4], bfv[4];
#pragma unroll
        for (int m = 0; m < 4; ++m)
            af[m] = load_bf8(&la[(wm0 + m * 16 + l15) * KP + l4 * 8]);
#pragma unroll
        for (int n = 0; n < 4; ++n)
            bfv[n] = load_bf8(&lb[(wn0 + n * 16 + l15) * KP + l4 * 8]);
#pragma unroll
        for (int m = 0; m < 4; ++m)
#pragma unroll
            for (int n = 0; n < 4; ++n)
                acc[m][n] = MFMA16(af[m], bfv[n], acc[m][n]);
        __syncthreads();
    }

    float bv4[4];
#pragma unroll
    for (int n = 0; n < 4; ++n) bv4[n] = bias[n0 + wn0 + n * 16 + l15];
    float nsq[4][4];
#pragma unroll
    for (int m = 0; m < 4; ++m)
#pragma unroll
        for (int r = 0; r < 4; ++r) nsq[m][r] = 0.f;

#pragma unroll
    for (int m = 0; m < 4; ++m) {
#pragma unroll
        for (int n = 0; n < 4; ++n) {
            int gcol = n0 + wn0 + n * 16 + l15;
#pragma unroll
            for (int r = 0; r < 4; ++r) {
                int grow = m0 + wm0 + m * 16 + l4 * 4 + r;
                float val = (acc[m][n][r] + bv4[n]) * outscale;
                nsq[m][r] += val * val;
                unsigned short ob = f2b(val);
                int b = grow >> 11, s = grow & 2047;
                int hh = gcol >> 6, dl = gcol & 63;
                if (mat == 0) {
                    Qp[(size_t)grow * DM + gcol] = ob;
                } else if (mat == 1) {
                    Kh[(((size_t)(b * NH + hh) * SEQ + s) << 6) + dl] = ob;
                } else {
                    Vt[(((size_t)(b * NH + hh) * DK + dl) << 11) + s] = ob;
                }
            }
        }
    }
    if (mat < 2) {
        const int hh = (n0 + wn0) >> 6;
#pragma unroll
        for (int m = 0; m < 4; ++m)
#pragma unroll
            for (int r = 0; r < 4; ++r) {
                float s2 = nsq[m][r];
                s2 += __shfl_xor(s2, 1);
                s2 += __shfl_xor(s2, 2);
                s2 += __shfl_xor(s2, 4);
                s2 += __shfl_xor(s2, 8);
                if (l15 == 0) {
                    int grow = m0 + wm0 + m * 16 + l4 * 4 + r;
                    int b = grow >> 11, s = grow & 2047;
                    float nrm = sqrtf(s2);
                    if (mat == 0)
                        qnorm[(b * NH + hh) * SEQ + s] = nrm;
                    else
                        atomicMax(&khmax[b * NH + hh], __float_as_uint(nrm));
                }
            }
    }
}

// ---------------------------------------------------------------- O projection
__global__ __launch_bounds__(256) void o_gemm(
        const unsigned short* __restrict__ Actx, const unsigned short* __restrict__ Wto,
        const float* __restrict__ bo, float* __restrict__ out) {
    constexpr int KP = 40;
    __shared__ unsigned short la[64 * KP];
    __shared__ unsigned short lb[128 * KP];
    const int tid = threadIdx.x;
    const int m0 = blockIdx.y * 64, n0 = blockIdx.x * 128;
    const int lane = tid & 63, wid = tid >> 6;
    const int wm0 = (wid >> 1) * 32, wn0 = (wid & 1) * 64;
    const int l15 = lane & 15, l4 = lane >> 4;
    f32x4 acc[2][4] = {};

    for (int kt = 0; kt < 32; ++kt) {
        const int k0 = kt * 32;
        {
            int row = tid >> 2, c8 = (tid & 3) * 8;
            *(int4*)&la[row * KP + c8] =
                *(const int4*)&Actx[(size_t)(m0 + row) * DM + k0 + c8];
        }
#pragma unroll
        for (int i = 0; i < 2; ++i) {
            int idx = tid + i * 256;
            int row = idx >> 2, c8 = (idx & 3) * 8;
            *(int4*)&lb[row * KP + c8] =
                *(const int4*)&Wto[(size_t)(n0 + row) * DM + k0 + c8];
        }
        __syncthreads();
        bf16x8 af[2], bfv[4];
#pragma unroll
        for (int m = 0; m < 2; ++m)
            af[m] = load_bf8(&la[(wm0 + m * 16 + l15) * KP + l4 * 8]);
#pragma unroll
        for (int n = 0; n < 4; ++n)
            bfv[n] = load_bf8(&lb[(wn0 + n * 16 + l15) * KP + l4 * 8]);
#pragma unroll
        for (int m = 0; m < 2; ++m)
#pragma unroll
            for (int n = 0; n < 4; ++n)
                acc[m][n] = MFMA16(af[m], bfv[n], acc[m][n]);
        __syncthreads();
    }

#pragma unroll
    for (int m = 0; m < 2; ++m)
#pragma unroll
        for (int n = 0; n < 4; ++n) {
            int gcol = n0 + wn0 + n * 16 + l15;
            float bb = bo[gcol];
#pragma unroll
            for (int r = 0; r < 4; ++r) {
                int grow = m0 + wm0 + m * 16 + l4 * 4 + r;
                out[(size_t)grow * DM + gcol] = acc[m][n][r] + bb;
            }
        }
}

// ---------------------------------------------------------------- attention
// Swapped-operand QK^T (lane holds P rows), safe-shift softmax (no online max),
// PV fused in pass 1 (unnormalized), pass 2 recompute + direct stores. No
// barriers/fences after the prologue.
__global__ __launch_bounds__(256) void attn4_kernel(
        const unsigned short* __restrict__ Qp, const unsigned short* __restrict__ Kh,
        const unsigned short* __restrict__ Vt, const float* __restrict__ bias_val,
        const float* __restrict__ qnorm, const unsigned int* __restrict__ khmax,
        float* __restrict__ attn_out, float* __restrict__ pb_out,
        unsigned short* __restrict__ ctx) {
    __shared__ float bias_lds[2112];
    __shared__ float redmax[4];
    const int tid = threadIdx.x;
    const int lane = tid & 63, wid = tid >> 6;
    const int l15 = lane & 15, l4 = lane >> 4;
    const int bid = (blockIdx.x & 7) * 128 + (blockIdx.x >> 3);  // XCD swizzle
    const int qb = bid & 31;
    const int h = (bid >> 5) & 15;
    const int b = bid >> 9;
    const int q0 = qb * 64;
    const int qw = q0 + wid * 16;
    const int bh = b * NH + h;

    float pmax = -1e30f;
    {
        const float* bp = bias_val + h * 4095 + (2047 - (q0 + 63));
        for (int i = tid; i < 2111; i += 256) {
            float x = bp[i];
            bias_lds[i] = x;
            pmax = fmaxf(pmax, x);
        }
    }
#pragma unroll
    for (int off = 1; off < 64; off <<= 1) pmax = fmaxf(pmax, __shfl_xor(pmax, off));
    if (lane == 0) redmax[wid] = pmax;
    __syncthreads();
    const float bmax = fmaxf(fmaxf(redmax[0], redmax[1]), fmaxf(redmax[2], redmax[3]));

    // Safe shift M >= row max: |q.k| <= |q||k| (1.01 covers bf16 rounding)
    const float M = qnorm[bh * SEQ + qw + l15] * 1.01f * __uint_as_float(khmax[bh])
                    + bmax + 0.1f;

    const unsigned short* qbase = Qp + (size_t)(b * SEQ + qw + l15) * DM + h * DK;
    bf16x8 qa0 = load_bf8(qbase + l4 * 8);
    bf16x8 qa1 = load_bf8(qbase + 32 + l4 * 8);
    const unsigned short* kbase = Kh + (((size_t)bh * SEQ) << 6);
    const unsigned short* vbase = Vt + (((size_t)bh * DK) << 11);
    const int ibb = 63 - wid * 16 - l15 + l4 * 4;   // bias idx = c0 + ch*16 + r + ibb

    // ---- pass 1: row sums + unnormalized PV
    float lsum = 0.f;
    f32x4 cacc[4] = {};
    const int sa = l15 + (((2 * l4) & 3) << 4);
    const int sb = sa + 16;
    for (int c0 = 0; c0 < SEQ; c0 += 32) {
        const unsigned short* kp = kbase + ((size_t)(c0 + l15) << 6);
        bf16x8 kb0 = load_bf8(kp + l4 * 8);
        bf16x8 kb1 = load_bf8(kp + 32 + l4 * 8);
        bf16x8 kb2 = load_bf8(kp + (16 << 6) + l4 * 8);
        bf16x8 kb3 = load_bf8(kp + (16 << 6) + 32 + l4 * 8);
        bf16x8 vv0 = load_bf8(vbase + ((size_t)(0 * 16 + l15) << 11) + c0 + l4 * 8);
        bf16x8 vv1 = load_bf8(vbase + ((size_t)(1 * 16 + l15) << 11) + c0 + l4 * 8);
        bf16x8 vv2 = load_bf8(vbase + ((size_t)(2 * 16 + l15) << 11) + c0 + l4 * 8);
        bf16x8 vv3 = load_bf8(vbase + ((size_t)(3 * 16 + l15) << 11) + c0 + l4 * 8);
        f32x4 a0 = {}, a1 = {};
        a0 = MFMA16(kb0, qa0, a0); a0 = MFMA16(kb1, qa1, a0);
        a1 = MFMA16(kb2, qa0, a1); a1 = MFMA16(kb3, qa1, a1);
        float e[8];
#pragma unroll
        for (int r = 0; r < 4; ++r) {
            e[r]     = __expf(a0[r] + bias_lds[c0 + r + ibb] - M);
            e[4 + r] = __expf(a1[r] + bias_lds[c0 + 16 + r + ibb] - M);
        }
        lsum += ((e[0] + e[1]) + (e[2] + e[3])) + ((e[4] + e[5]) + (e[6] + e[7]));
        unsigned u0 = ((unsigned)f2b(e[1]) << 16) | f2b(e[0]);
        unsigned u1 = ((unsigned)f2b(e[3]) << 16) | f2b(e[2]);
        unsigned u2 = ((unsigned)f2b(e[5]) << 16) | f2b(e[4]);
        unsigned u3 = ((unsigned)f2b(e[7]) << 16) | f2b(e[6]);
        unsigned A0 = (unsigned)__shfl((int)u0, sa), A1 = (unsigned)__shfl((int)u1, sa);
        unsigned A2 = (unsigned)__shfl((int)u2, sa), A3 = (unsigned)__shfl((int)u3, sa);
        unsigned B0 = (unsigned)__shfl((int)u0, sb), B1 = (unsigned)__shfl((int)u1, sb);
        unsigned B2 = (unsigned)__shfl((int)u2, sb), B3 = (unsigned)__shfl((int)u3, sb);
        const bool lo = l4 < 2;
        uint4 wv;
        wv.x = lo ? A0 : A2;
        wv.y = lo ? A1 : A3;
        wv.z = lo ? B0 : B2;
        wv.w = lo ? B1 : B3;
        bf16x8 pf = __builtin_bit_cast(bf16x8, wv);
        cacc[0] = MFMA16(pf, vv0, cacc[0]);
        cacc[1] = MFMA16(pf, vv1, cacc[1]);
        cacc[2] = MFMA16(pf, vv2, cacc[2]);
        cacc[3] = MFMA16(pf, vv3, cacc[3]);
    }
    lsum += __shfl_xor(lsum, 16);
    lsum += __shfl_xor(lsum, 32);
    const float invl = 1.0f / lsum;
    const float Mlog = M + __logf(lsum);

    // ctx write: need invl of row l4*4+r (lives in lane l4*4+r)
    float invr[4];
#pragma unroll
    for (int r = 0; r < 4; ++r) invr[r] = __shfl(invl, l4 * 4 + r);
#pragma unroll
    for (int d0 = 0; d0 < 4; ++d0)
#pragma unroll
        for (int r = 0; r < 4; ++r)
            ctx[(size_t)(b * SEQ + qw + l4 * 4 + r) * DM + h * DK + d0 * 16 + l15] =
                f2b(cacc[d0][r] * invr[r]);

    // ---- pass 2: recompute scores, store normalized weights + pb
    float* abase = attn_out + ((size_t)(bh * SEQ + qw + l15)) * SEQ;
    float* pbase = pb_out + ((size_t)(bh * SEQ + qw + l15)) * SEQ;
    for (int c0 = 0; c0 < SEQ; c0 += 32) {
        const unsigned short* kp = kbase + ((size_t)(c0 + l15) << 6);
        bf16x8 kb0 = load_bf8(kp + l4 * 8);
        bf16x8 kb1 = load_bf8(kp + 32 + l4 * 8);
        bf16x8 kb2 = load_bf8(kp + (16 << 6) + l4 * 8);
        bf16x8 kb3 = load_bf8(kp + (16 << 6) + 32 + l4 * 8);
        f32x4 a0 = {}, a1 = {};
        a0 = MFMA16(kb0, qa0, a0); a0 = MFMA16(kb1, qa1, a0);
        a1 = MFMA16(kb2, qa0, a1); a1 = MFMA16(kb3, qa1, a1);
        float4 b0, b1;
        b0.x = bias_lds[c0 + 0 + ibb]; b0.y = bias_lds[c0 + 1 + ibb];
        b0.z = bias_lds[c0 + 2 + ibb]; b0.w = bias_lds[c0 + 3 + ibb];
        b1.x = bias_lds[c0 + 16 + ibb]; b1.y = bias_lds[c0 + 17 + ibb];
        b1.z = bias_lds[c0 + 18 + ibb]; b1.w = bias_lds[c0 + 19 + ibb];
        float4 f0, f1;
        f0.x = __expf(a0[0] + b0.x - Mlog);
        f0.y = __expf(a0[1] + b0.y - Mlog);
        f0.z = __expf(a0[2] + b0.z - Mlog);
        f0.w = __expf(a0[3] + b0.w - Mlog);
        f1.x = __expf(a1[0] + b1.x - Mlog);
        f1.y = __expf(a1[1] + b1.y - Mlog);
        f1.z = __expf(a1[2] + b1.z - Mlog);
        f1.w = __expf(a1[3] + b1.w - Mlog);
        *(float4*)(abase + c0 + l4 * 4) = f0;
        *(float4*)(abase + c0 + 16 + l4 * 4) = f1;
        *(float4*)(pbase + c0 + l4 * 4) = b0;
        *(float4*)(pbase + c0 + 16 + l4 * 4) = b1;
    }
}

// ---------------------------------------------------------------- launcher
extern "C" void kernel_launch(void* const* d_in, const int* in_sizes, int n_in,
                              void* d_out, int out_size, void* d_ws, size_t ws_size,
                              hipStream_t stream) {
    const float* query = (const float*)d_in[0];
    const float* key   = (const float*)d_in[1];
    const float* value = (const float*)d_in[2];
    const float* Wq = (const float*)d_in[3];
    const float* bq = (const float*)d_in[4];
    const float* Wk = (const float*)d_in[5];
    const float* bk = (const float*)d_in[6];
    const float* Wv = (const float*)d_in[7];
    const float* bv = (const float*)d_in[8];
    const float* Wo = (const float*)d_in[9];
    const float* bo = (const float*)d_in[10];
    const float* rel = (const float*)d_in[11];

    float* out = (float*)d_out;
    float* attn_out = out + (size_t)BN * SEQ * DM;
    float* pb_out = attn_out + (size_t)BN * NH * SEQ * SEQ;

    char* ws = (char*)d_ws;
    float* bias_val = (float*)ws;                                   // 256KB slot
    unsigned short* Qp  = (unsigned short*)(ws + 262144);
    unsigned short* Kh  = Qp + (size_t)BN * SEQ * DM;
    unsigned short* Vt  = Kh + (size_t)BN * SEQ * DM;
    unsigned short* ctx = Vt + (size_t)BN * SEQ * DM;
    unsigned short* Wtq = ctx + (size_t)BN * SEQ * DM;
    unsigned short* Wtk = Wtq + (size_t)DM * DM;
    unsigned short* Wtv = Wtk + (size_t)DM * DM;
    unsigned short* Wto = Wtv + (size_t)DM * DM;
    float* qnorm = (float*)(Wto + (size_t)DM * DM);                 // 256KB
    unsigned int* khmax = (unsigned int*)(qnorm + (size_t)BN * NH * SEQ);

    bias_table_kernel<<<256, 256, 0, stream>>>(rel, bias_val, khmax);
    wtrans_kernel<<<dim3(16, 16, 4), 256, 0, stream>>>(Wq, Wk, Wv, Wo, Wtq, Wtk, Wtv, Wto);
    qkv_gemm<<<dim3(8, 32, 3), 256, 0, stream>>>(query, key, value, Wtq, Wtk, Wtv,
                                                 bq, bk, bv, Qp, Kh, Vt, qnorm, khmax);
    attn4_kernel<<<BN * NH * (SEQ / 64), 256, 0, stream>>>(Qp, Kh, Vt, bias_val,
                                                           qnorm, khmax,
                                                           attn_out, pb_out, ctx);
    o_gemm<<<dim3(8, 64), 256, 0, stream>>>(ctx, Wto, bo, out);
}

// Round 5
// 592.766 us; speedup vs baseline: 1.7823x; 1.7823x over previous
//
#include <hip/hip_runtime.h>
#include <hip/hip_bf16.h>

#define BN 2
#define SEQ 2048
#define DM 1024
#define NH 16
#define DK 64

using f32x4  = __attribute__((ext_vector_type(4))) float;
using bf16x8 = __attribute__((ext_vector_type(8))) __bf16;
using short8 = __attribute__((ext_vector_type(8))) short;

static_assert(sizeof(bf16x8) == 16, "bf16x8 must be 16B");

#define MFMA16(a, b, c) __builtin_amdgcn_mfma_f32_16x16x32_bf16(a, b, c, 0, 0, 0)

__device__ __forceinline__ unsigned short f2b(float f) {
    __hip_bfloat16 h = __float2bfloat16(f);
    return __builtin_bit_cast(unsigned short, h);
}

__device__ __forceinline__ bf16x8 load_bf8(const unsigned short* p) {
    short8 s = *reinterpret_cast<const short8*>(p);
    return __builtin_bit_cast(bf16x8, s);
}

// ---------------------------------------------------------------- bias table
__global__ void bias_table_kernel(const float* __restrict__ rel,
                                  float* __restrict__ bias_val) {
    int idx = blockIdx.x * 256 + threadIdx.x;
    if (idx >= NH * 4095) return;
    int h = idx / 4095;
    int dd = idx - h * 4095;
    int d = dd - 2047;
    int a = d < 0 ? -d : d;
    int bucket;
    if (a == 0) bucket = 0;
    else if (a < 8) bucket = 16 + a;
    else {
        int k = (a >= 14) + (a >= 23) + (a >= 39) + (a >= 64) +
                (a >= 108) + (a >= 182) + (a >= 305);
        bucket = 24 + k;
    }
    bias_val[h * 4095 + dd] = rel[bucket * NH + h];
}

// ---------------------------------------------------------------- weight prep
__global__ __launch_bounds__(256) void wtrans_kernel(
        const float* __restrict__ W0, const float* __restrict__ W1,
        const float* __restrict__ W2, const float* __restrict__ W3,
        unsigned short* __restrict__ T0, unsigned short* __restrict__ T1,
        unsigned short* __restrict__ T2, unsigned short* __restrict__ T3) {
    constexpr int P = 68;
    __shared__ unsigned short lt[64 * P];
    const int mz = blockIdx.z;
    const float* W = mz == 0 ? W0 : mz == 1 ? W1 : mz == 2 ? W2 : W3;
    unsigned short* T = mz == 0 ? T0 : mz == 1 ? T1 : mz == 2 ? T2 : T3;
    const int k0 = blockIdx.x * 64, n0 = blockIdx.y * 64;
    const int tid = threadIdx.x;
#pragma unroll
    for (int p = 0; p < 4; ++p) {
        int r = p * 16 + (tid >> 4);
        int c = (tid & 15) * 4;
        float4 vv = *(const float4*)&W[(size_t)(k0 + r) * DM + n0 + c];
#pragma unroll
        for (int j = 0; j < 4; ++j) {
            int n = c + j;
            float x = j == 0 ? vv.x : j == 1 ? vv.y : j == 2 ? vv.z : vv.w;
            lt[n * P + (r ^ ((n & 7) << 3))] = f2b(x);
        }
    }
    __syncthreads();
#pragma unroll
    for (int p = 0; p < 2; ++p) {
        int rn = p * 32 + (tid >> 3);
        int ck = (tid & 7) * 8;
        int ckx = ck ^ ((rn & 7) << 3);
        ushort4 a0 = *(ushort4*)&lt[rn * P + ckx];
        ushort4 a1 = *(ushort4*)&lt[rn * P + ckx + 4];
        *(ushort4*)&T[(size_t)(n0 + rn) * DM + k0 + ck] = a0;
        *(ushort4*)&T[(size_t)(n0 + rn) * DM + k0 + ck + 4] = a1;
    }
}

// ---------------------------------------------------------------- fused QKV GEMM
// z=0: Q natural bf16 *0.125; z=1: K head-major Kh[b][h][s][d]; z=2: V -> Vt[b][h][d][s]
__global__ __launch_bounds__(256) void qkv_gemm(
        const float* __restrict__ Aq, const float* __restrict__ Ak, const float* __restrict__ Av,
        const unsigned short* __restrict__ Wtq, const unsigned short* __restrict__ Wtk,
        const unsigned short* __restrict__ Wtv,
        const float* __restrict__ bq, const float* __restrict__ bk, const float* __restrict__ bv,
        unsigned short* __restrict__ Qp, unsigned short* __restrict__ Kh,
        unsigned short* __restrict__ Vt) {
    constexpr int KP = 40;
    __shared__ unsigned short la[128 * KP];
    __shared__ unsigned short lb[128 * KP];
    const int mat = blockIdx.z;
    const float* A = mat == 0 ? Aq : mat == 1 ? Ak : Av;
    const unsigned short* Wt = mat == 0 ? Wtq : mat == 1 ? Wtk : Wtv;
    const float* bias = mat == 0 ? bq : mat == 1 ? bk : bv;
    const float outscale = mat == 0 ? 0.125f : 1.0f;
    const int tid = threadIdx.x;
    const int m0 = blockIdx.y * 128, n0 = blockIdx.x * 128;
    const int lane = tid & 63, wid = tid >> 6;
    const int wm0 = (wid >> 1) * 64, wn0 = (wid & 1) * 64;
    const int l15 = lane & 15, l4 = lane >> 4;
    f32x4 acc[4][4] = {};

    for (int kt = 0; kt < 32; ++kt) {
        const int k0 = kt * 32;
#pragma unroll
        for (int i = 0; i < 4; ++i) {
            int idx = tid + i * 256;
            int row = idx >> 3, c4 = (idx & 7) * 4;
            float4 v = *(const float4*)(A + (size_t)(m0 + row) * DM + k0 + c4);
            ushort4 u; u.x = f2b(v.x); u.y = f2b(v.y); u.z = f2b(v.z); u.w = f2b(v.w);
            *(ushort4*)&la[row * KP + c4] = u;
        }
#pragma unroll
        for (int i = 0; i < 2; ++i) {
            int idx = tid + i * 256;
            int row = idx >> 2, c8 = (idx & 3) * 8;
            *(int4*)&lb[row * KP + c8] =
                *(const int4*)&Wt[(size_t)(n0 + row) * DM + k0 + c8];
        }
        __syncthreads();
        bf16x8 af[4], bfv[4];
#pragma unroll
        for (int m = 0; m < 4; ++m)
            af[m] = load_bf8(&la[(wm0 + m * 16 + l15) * KP + l4 * 8]);
#pragma unroll
        for (int n = 0; n < 4; ++n)
            bfv[n] = load_bf8(&lb[(wn0 + n * 16 + l15) * KP + l4 * 8]);
#pragma unroll
        for (int m = 0; m < 4; ++m)
#pragma unroll
            for (int n = 0; n < 4; ++n)
                acc[m][n] = MFMA16(af[m], bfv[n], acc[m][n]);
        __syncthreads();
    }

    float bv4[4];
#pragma unroll
    for (int n = 0; n < 4; ++n) bv4[n] = bias[n0 + wn0 + n * 16 + l15];
#pragma unroll
    for (int m = 0; m < 4; ++m) {
#pragma unroll
        for (int n = 0; n < 4; ++n) {
            int gcol = n0 + wn0 + n * 16 + l15;
#pragma unroll
            for (int r = 0; r < 4; ++r) {
                int grow = m0 + wm0 + m * 16 + l4 * 4 + r;
                float val = (acc[m][n][r] + bv4[n]) * outscale;
                unsigned short ob = f2b(val);
                int b = grow >> 11, s = grow & 2047;
                int hh = gcol >> 6, dl = gcol & 63;
                if (mat == 0) {
                    Qp[(size_t)grow * DM + gcol] = ob;
                } else if (mat == 1) {
                    Kh[(((size_t)(b * NH + hh) * SEQ + s) << 6) + dl] = ob;
                } else {
                    Vt[(((size_t)(b * NH + hh) * DK + dl) << 11) + s] = ob;
                }
            }
        }
    }
}

// ---------------------------------------------------------------- O projection
__global__ __launch_bounds__(256) void o_gemm(
        const unsigned short* __restrict__ Actx, const unsigned short* __restrict__ Wto,
        const float* __restrict__ bo, float* __restrict__ out) {
    constexpr int KP = 40;
    __shared__ unsigned short la[64 * KP];
    __shared__ unsigned short lb[128 * KP];
    const int tid = threadIdx.x;
    const int m0 = blockIdx.y * 64, n0 = blockIdx.x * 128;
    const int lane = tid & 63, wid = tid >> 6;
    const int wm0 = (wid >> 1) * 32, wn0 = (wid & 1) * 64;
    const int l15 = lane & 15, l4 = lane >> 4;
    f32x4 acc[2][4] = {};

    for (int kt = 0; kt < 32; ++kt) {
        const int k0 = kt * 32;
        {
            int row = tid >> 2, c8 = (tid & 3) * 8;
            *(int4*)&la[row * KP + c8] =
                *(const int4*)&Actx[(size_t)(m0 + row) * DM + k0 + c8];
        }
#pragma unroll
        for (int i = 0; i < 2; ++i) {
            int idx = tid + i * 256;
            int row = idx >> 2, c8 = (idx & 3) * 8;
            *(int4*)&lb[row * KP + c8] =
                *(const int4*)&Wto[(size_t)(n0 + row) * DM + k0 + c8];
        }
        __syncthreads();
        bf16x8 af[2], bfv[4];
#pragma unroll
        for (int m = 0; m < 2; ++m)
            af[m] = load_bf8(&la[(wm0 + m * 16 + l15) * KP + l4 * 8]);
#pragma unroll
        for (int n = 0; n < 4; ++n)
            bfv[n] = load_bf8(&lb[(wn0 + n * 16 + l15) * KP + l4 * 8]);
#pragma unroll
        for (int m = 0; m < 2; ++m)
#pragma unroll
            for (int n = 0; n < 4; ++n)
                acc[m][n] = MFMA16(af[m], bfv[n], acc[m][n]);
        __syncthreads();
    }

#pragma unroll
    for (int m = 0; m < 2; ++m)
#pragma unroll
        for (int n = 0; n < 4; ++n) {
            int gcol = n0 + wn0 + n * 16 + l15;
            float bb = bo[gcol];
#pragma unroll
            for (int r = 0; r < 4; ++r) {
                int grow = m0 + wm0 + m * 16 + l4 * 4 + r;
                out[(size_t)grow * DM + gcol] = acc[m][n][r] + bb;
            }
        }
}

// ---------------------------------------------------------------- attention
// Round-3 structure (two-pass online softmax, wtile for store coalescing +
// P transpose, fused pb) with DOUBLE-BUFFERED wtile: one lgkmcnt drain per
// iteration instead of two (no WAR hazard across iterations).
__global__ __launch_bounds__(256, 4) void attn5_kernel(
        const unsigned short* __restrict__ Qp, const unsigned short* __restrict__ Kh,
        const unsigned short* __restrict__ Vt, const float* __restrict__ bias_val,
        float* __restrict__ attn_out, float* __restrict__ pb_out,
        unsigned short* __restrict__ ctx) {
    __shared__ float bias_lds[2112];
    __shared__ float wtile[2][4][16 * 36];
    const int tid = threadIdx.x;
    const int lane = tid & 63, wid = tid >> 6;
    const int l15 = lane & 15, l4 = lane >> 4;
    const int bid = (blockIdx.x & 7) * 128 + (blockIdx.x >> 3);  // XCD swizzle
    const int qb = bid & 31;
    const int h = (bid >> 5) & 15;
    const int b = bid >> 9;
    const int q0 = qb * 64;
    const int qw = q0 + wid * 16;

    {
        const float* bp = bias_val + h * 4095 + (2047 - (q0 + 63));
        for (int i = tid; i < 2111; i += 256) bias_lds[i] = bp[i];
    }
    __syncthreads();

    const unsigned short* qbase = Qp + (size_t)(b * SEQ + qw + l15) * DM + h * DK;
    bf16x8 qa0 = load_bf8(qbase + l4 * 8);
    bf16x8 qa1 = load_bf8(qbase + 32 + l4 * 8);

    const unsigned short* kbase = Kh + (((size_t)(b * NH + h) * SEQ) << 6);
    const int bbase = 63 - wid * 16 - l4 * 4;

    float m[4], l[4];
#pragma unroll
    for (int r = 0; r < 4; ++r) { m[r] = -3e38f; l[r] = 0.f; }

    // ---- pass 1
    for (int c0 = 0; c0 < SEQ; c0 += 32) {
        const unsigned short* kp = kbase + ((size_t)(c0 + l15) << 6);
        bf16x8 k00 = load_bf8(kp + l4 * 8);
        bf16x8 k01 = load_bf8(kp + 32 + l4 * 8);
        bf16x8 k10 = load_bf8(kp + (16 << 6) + l4 * 8);
        bf16x8 k11 = load_bf8(kp + (16 << 6) + 32 + l4 * 8);
        f32x4 a0 = {}, a1 = {};
        a0 = MFMA16(qa0, k00, a0); a0 = MFMA16(qa1, k01, a0);
        a1 = MFMA16(qa0, k10, a1); a1 = MFMA16(qa1, k11, a1);
#pragma unroll
        for (int r = 0; r < 4; ++r) {
            float s0 = a0[r] + bias_lds[c0 + l15 + bbase - r];
            float s1 = a1[r] + bias_lds[c0 + 16 + l15 + bbase - r];
            float cm = fmaxf(s0, s1);
            if (cm > m[r]) { l[r] *= __expf(m[r] - cm); m[r] = cm; }
            l[r] += __expf(s0 - m[r]) + __expf(s1 - m[r]);
        }
    }
#pragma unroll
    for (int off = 1; off < 16; off <<= 1) {
#pragma unroll
        for (int r = 0; r < 4; ++r) {
            float om = __shfl_xor(m[r], off);
            float ol = __shfl_xor(l[r], off);
            float M = fmaxf(m[r], om);
            l[r] = l[r] * __expf(m[r] - M) + ol * __expf(om - M);
            m[r] = M;
        }
    }
    float invl[4];
#pragma unroll
    for (int r = 0; r < 4; ++r) invl[r] = 1.0f / l[r];

    // ---- pass 2
    float* abase = attn_out + ((size_t)((b * NH + h) * SEQ + qw)) * SEQ;
    float* pbase = pb_out + ((size_t)((b * NH + h) * SEQ + qw)) * SEQ;
    const unsigned short* vbase = Vt + (((size_t)(b * NH + h) * DK) << 11);
    f32x4 cacc[4] = {};

    bf16x8 k00, k01, k10, k11;
    {
        const unsigned short* kp = kbase + ((size_t)l15 << 6);
        k00 = load_bf8(kp + l4 * 8);
        k01 = load_bf8(kp + 32 + l4 * 8);
        k10 = load_bf8(kp + (16 << 6) + l4 * 8);
        k11 = load_bf8(kp + (16 << 6) + 32 + l4 * 8);
    }
    const int srow = lane >> 2, scg = (lane & 3) * 8;
    int cur = 0;
    for (int c0 = 0; c0 < SEQ; c0 += 32, cur ^= 1) {
        f32x4 a0 = {}, a1 = {};
        a0 = MFMA16(qa0, k00, a0); a0 = MFMA16(qa1, k01, a0);
        a1 = MFMA16(qa0, k10, a1); a1 = MFMA16(qa1, k11, a1);
        const int cn = (c0 + 32) & (SEQ - 1);
        const unsigned short* kp = kbase + ((size_t)(cn + l15) << 6);
        k00 = load_bf8(kp + l4 * 8);
        k01 = load_bf8(kp + 32 + l4 * 8);
        k10 = load_bf8(kp + (16 << 6) + l4 * 8);
        k11 = load_bf8(kp + (16 << 6) + 32 + l4 * 8);
        bf16x8 vv0 = load_bf8(vbase + ((size_t)(0 * 16 + l15) << 11) + c0 + l4 * 8);
        bf16x8 vv1 = load_bf8(vbase + ((size_t)(1 * 16 + l15) << 11) + c0 + l4 * 8);
        bf16x8 vv2 = load_bf8(vbase + ((size_t)(2 * 16 + l15) << 11) + c0 + l4 * 8);
        bf16x8 vv3 = load_bf8(vbase + ((size_t)(3 * 16 + l15) << 11) + c0 + l4 * 8);
        float* wt = wtile[cur][wid];
#pragma unroll
        for (int r = 0; r < 4; ++r) {
            int row = l4 * 4 + r;
            float w0 = __expf(a0[r] + bias_lds[c0 + l15 + bbase - r] - m[r]) * invl[r];
            float w1 = __expf(a1[r] + bias_lds[c0 + 16 + l15 + bbase - r] - m[r]) * invl[r];
            wt[row * 36 + l15] = w0;
            wt[row * 36 + 16 + l15] = w1;
        }
        // single write->read drain; next iteration writes the other buffer
        asm volatile("s_waitcnt lgkmcnt(0)" ::: "memory");
        __builtin_amdgcn_sched_barrier(0);
        {   // attn weights: 16 rows x 128B segments
            float4 v0 = *(const float4*)&wt[srow * 36 + scg];
            float4 v1 = *(const float4*)&wt[srow * 36 + scg + 4];
            float* gp = abase + (size_t)srow * SEQ + c0 + scg;
            *(float4*)gp = v0;
            *(float4*)(gp + 4) = v1;
        }
        {   // fused pb slice from bias_lds diagonals
            const int ib = c0 + scg + bbase + l4 * 4 - srow;
            float4 p0, p1;
            p0.x = bias_lds[ib + 0]; p0.y = bias_lds[ib + 1];
            p0.z = bias_lds[ib + 2]; p0.w = bias_lds[ib + 3];
            p1.x = bias_lds[ib + 4]; p1.y = bias_lds[ib + 5];
            p1.z = bias_lds[ib + 6]; p1.w = bias_lds[ib + 7];
            float* gp = pbase + (size_t)srow * SEQ + c0 + scg;
            *(float4*)gp = p0;
            *(float4*)(gp + 4) = p1;
        }
        float4 pA = *(const float4*)&wt[l15 * 36 + l4 * 8];
        float4 pB = *(const float4*)&wt[l15 * 36 + l4 * 8 + 4];
        short8 ps;
        ps[0] = (short)f2b(pA.x); ps[1] = (short)f2b(pA.y);
        ps[2] = (short)f2b(pA.z); ps[3] = (short)f2b(pA.w);
        ps[4] = (short)f2b(pB.x); ps[5] = (short)f2b(pB.y);
        ps[6] = (short)f2b(pB.z); ps[7] = (short)f2b(pB.w);
        bf16x8 pf = __builtin_bit_cast(bf16x8, ps);
        cacc[0] = MFMA16(pf, vv0, cacc[0]);
        cacc[1] = MFMA16(pf, vv1, cacc[1]);
        cacc[2] = MFMA16(pf, vv2, cacc[2]);
        cacc[3] = MFMA16(pf, vv3, cacc[3]);
    }
#pragma unroll
    for (int d0 = 0; d0 < 4; ++d0)
#pragma unroll
        for (int r = 0; r < 4; ++r)
            ctx[(size_t)(b * SEQ + qw + l4 * 4 + r) * DM + h * DK + d0 * 16 + l15] =
                f2b(cacc[d0][r]);
}

// ---------------------------------------------------------------- launcher
extern "C" void kernel_launch(void* const* d_in, const int* in_sizes, int n_in,
                              void* d_out, int out_size, void* d_ws, size_t ws_size,
                              hipStream_t stream) {
    const float* query = (const float*)d_in[0];
    const float* key   = (const float*)d_in[1];
    const float* value = (const float*)d_in[2];
    const float* Wq = (const float*)d_in[3];
    const float* bq = (const float*)d_in[4];
    const float* Wk = (const float*)d_in[5];
    const float* bk = (const float*)d_in[6];
    const float* Wv = (const float*)d_in[7];
    const float* bv = (const float*)d_in[8];
    const float* Wo = (const float*)d_in[9];
    const float* bo = (const float*)d_in[10];
    const float* rel = (const float*)d_in[11];

    float* out = (float*)d_out;
    float* attn_out = out + (size_t)BN * SEQ * DM;
    float* pb_out = attn_out + (size_t)BN * NH * SEQ * SEQ;

    char* ws = (char*)d_ws;
    float* bias_val = (float*)ws;                                   // 256KB slot
    unsigned short* Qp  = (unsigned short*)(ws + 262144);
    unsigned short* Kh  = Qp + (size_t)BN * SEQ * DM;
    unsigned short* Vt  = Kh + (size_t)BN * SEQ * DM;
    unsigned short* ctx = Vt + (size_t)BN * SEQ * DM;
    unsigned short* Wtq = ctx + (size_t)BN * SEQ * DM;
    unsigned short* Wtk = Wtq + (size_t)DM * DM;
    unsigned short* Wtv = Wtk + (size_t)DM * DM;
    unsigned short* Wto = Wtv + (size_t)DM * DM;

    bias_table_kernel<<<256, 256, 0, stream>>>(rel, bias_val);
    wtrans_kernel<<<dim3(16, 16, 4), 256, 0, stream>>>(Wq, Wk, Wv, Wo, Wtq, Wtk, Wtv, Wto);
    qkv_gemm<<<dim3(8, 32, 3), 256, 0, stream>>>(query, key, value, Wtq, Wtk, Wtv,
                                                 bq, bk, bv, Qp, Kh, Vt);
    attn5_kernel<<<BN * NH * (SEQ / 64), 256, 0, stream>>>(Qp, Kh, Vt, bias_val,
                                                           attn_out, pb_out, ctx);
    o_gemm<<<dim3(8, 64), 256, 0, stream>>>(ctx, Wto, bo, out);
}